// Round 13
// baseline (90.382 us; speedup 1.0000x reference)
//
#include <hip/hip_runtime.h>

#define N_VERT 50000
#define KNBR 20
#define F 128
#define NBLK 782        // ceil(50000/64)
#define AGG_BLOCKS 3125 // N_VERT/16
#define PASS_BLOCKS 1024

typedef unsigned int uint32;
typedef unsigned short ushort16;
typedef unsigned char uint8;
typedef __attribute__((ext_vector_type(8))) short bf16x8;
typedef __attribute__((ext_vector_type(4))) float f32x4;
typedef __attribute__((ext_vector_type(2))) float f32x2;

__device__ __forceinline__ uint32 f2bf_bits(float x) {
    uint32 u = __float_as_uint(x);
    u += 0x7fff + ((u >> 16) & 1);        // round-to-nearest-even
    return u >> 16;
}

// ---------------------------------------------------------------------------
// Kernel W: weights -> bf16 fragment-linear Wt + permuted bias bvp.
// Permuted column order: c' = lr*8 + nt  <->  filter nt*16 + lr.
// ---------------------------------------------------------------------------
__global__ __launch_bounds__(256) void wconv_kernel(
    const float* __restrict__ Wc, const float* __restrict__ Wi,
    const float* __restrict__ Wn, const float* __restrict__ bv,
    ushort16* __restrict__ Wt, float* __restrict__ bvp)
{
    int t = blockIdx.x * 256 + threadIdx.x;
    if (blockIdx.x == 0 && threadIdx.x < 128) {
        int c = threadIdx.x;                    // c' = lr*8+nt
        bvp[c] = bv[(c & 7) * 16 + (c >> 3)];   // filter nt*16+lr
    }
    if (t >= 3 * F * F) return;
    int w    = t >> 14;
    int r    = t & 16383;
    int kk   = r >> 12;
    int r2   = r & 4095;
    int nt   = r2 >> 9;
    int r3   = r2 & 511;
    int lane = r3 >> 3;
    int e    = r3 & 7;
    int k = kk * 32 + (lane >> 4) * 8 + e;
    int n = nt * 16 + (lane & 15);
    const float* W = (w == 0) ? Wc : ((w == 1) ? Wi : Wn);
    Wt[t] = (ushort16)f2bf_bits(W[k * F + n]);
}

// ---------------------------------------------------------------------------
// Kernel A: FUSED projections, SEQUENTIAL-w phases + per-phase LDS staging.
// vert read ONCE (afrag built once); one 8-acc set live (~90 regs, no cap
// pragma -> no spill risk); B-operands via conflict-free LDS (ds_read_b128,
// ~12cy) staged 32 KB/phase from fragment-linear Wt. Stage-loads issued
// BEFORE the WAR barrier so global latency hides under it.
// Register-direct permuted stores (c' = lr*8+nt):
//   w==0 -> zcp bf16[N][128] with bias pre-added
//   w==1/2 -> fp8 e4m3 [N][128] via HW cvt_pk_fp8_f32
// ---------------------------------------------------------------------------
__global__ __launch_bounds__(256) void mfma_proj_kernel(
    const float*    __restrict__ vert,
    const ushort16* __restrict__ Wt,
    const float*    __restrict__ bvp,
    ushort16* __restrict__ zcp,
    uint8* __restrict__ pay_i,
    uint8* __restrict__ pay_n)
{
    __shared__ uint4 wlds[32 * 64];   // 32 KB: one w's 32 B-fragments

    const int wave = threadIdx.x >> 6;
    const int lane = threadIdx.x & 63;
    const int lr   = lane & 15;
    const int lk   = lane >> 4;
    const int rb   = (blockIdx.x * 4 + wave) * 16;

    // ---- A fragments: V rows read ONCE, converted inline (clamped tail) ----
    int rowA = rb + lr; if (rowA > N_VERT - 1) rowA = N_VERT - 1;
    const float* vrow = vert + (size_t)rowA * F;
    bf16x8 afrag[4];
#pragma unroll
    for (int kk = 0; kk < 4; ++kk) {
        const float* p = vrow + kk * 32 + lk * 8;
        f32x4 lo = *(const f32x4*)p;
        f32x4 hi = *(const f32x4*)(p + 4);
#pragma unroll
        for (int j = 0; j < 4; ++j) {
            afrag[kk][j]     = (short)f2bf_bits(lo[j]);
            afrag[kk][4 + j] = (short)f2bf_bits(hi[j]);
        }
    }

    const uint4* gW = (const uint4*)Wt + lane;   // fragment base for this lane

#pragma unroll
    for (int w = 0; w < 3; ++w) {
        // ---- stage phase w: wave stages kk=wave (8x uint4 load + ds_write) ----
        uint4 st[8];
#pragma unroll
        for (int nt = 0; nt < 8; ++nt)
            st[nt] = gW[(size_t)((w * 4 + wave) * 8 + nt) * 64];
        __syncthreads();   // WAR: prior phase's ds_reads done (loads in flight)
#pragma unroll
        for (int nt = 0; nt < 8; ++nt)
            wlds[(wave * 8 + nt) * 64 + lane] = st[nt];
        __syncthreads();   // staging visible

        f32x4 acc[8];
#pragma unroll
        for (int nt = 0; nt < 8; ++nt) acc[nt] = (f32x4)(0.f);

#pragma unroll
        for (int kk = 0; kk < 4; ++kk)
#pragma unroll
            for (int nt = 0; nt < 8; ++nt) {
                bf16x8 b = *(const bf16x8*)&wlds[(kk * 8 + nt) * 64 + lane];
                acc[nt] = __builtin_amdgcn_mfma_f32_16x16x32_bf16(
                    afrag[kk], b, acc[nt], 0, 0, 0);
            }

        if (w == 0) {
            // bias pre-add (filter nt*16+lr -> bvp[lr*8+nt]), bf16 permuted store
            f32x4 bb0 = *(const f32x4*)(bvp + lr * 8);
            f32x4 bb1 = *(const f32x4*)(bvp + lr * 8 + 4);
            float bbv[8] = {bb0[0], bb0[1], bb0[2], bb0[3],
                            bb1[0], bb1[1], bb1[2], bb1[3]};
#pragma unroll
            for (int j = 0; j < 4; ++j) {
                int row = rb + lk * 4 + j;
                if (row >= N_VERT) continue;
                uint32 d[4];
#pragma unroll
                for (int p = 0; p < 4; ++p)
                    d[p] = f2bf_bits(acc[2 * p][j] + bbv[2 * p]) |
                           (f2bf_bits(acc[2 * p + 1][j] + bbv[2 * p + 1]) << 16);
                *(uint4*)((uint8*)zcp + (size_t)row * 256 + lr * 16) =
                    make_uint4(d[0], d[1], d[2], d[3]);
            }
        } else {
            uint8* pay = (w == 1) ? pay_i : pay_n;
#pragma unroll
            for (int j = 0; j < 4; ++j) {
                int row = rb + lk * 4 + j;
                if (row >= N_VERT) continue;
                uint32 lo, hi;
                lo = __builtin_amdgcn_cvt_pk_fp8_f32(acc[0][j], acc[1][j], 0, false);
                lo = __builtin_amdgcn_cvt_pk_fp8_f32(acc[2][j], acc[3][j], lo, true);
                hi = __builtin_amdgcn_cvt_pk_fp8_f32(acc[4][j], acc[5][j], 0, false);
                hi = __builtin_amdgcn_cvt_pk_fp8_f32(acc[6][j], acc[7][j], hi, true);
                *(uint2*)(pay + (size_t)row * 128 + lr * 8) = make_uint2(lo, hi);
            }
        }
    }
}

// ---------------------------------------------------------------------------
// Kernel B: gather-aggregate (fp8 payload) + FOLDED passthrough. (unchanged)
// ---------------------------------------------------------------------------
__global__ __launch_bounds__(256) void agg_kernel(
    const uint8*  __restrict__ pay_i,
    const uint8*  __restrict__ pay_n,
    const unsigned short* __restrict__ zcp,
    const int4*   __restrict__ int_idx4,
    const int4*   __restrict__ nh_idx4,
    const float4* __restrict__ int_e4,
    const float4* __restrict__ nh_e4,
    float* __restrict__ z,
    const int*   __restrict__ nh_idx,  const int*   __restrict__ int_idx,
    const float* __restrict__ nh_e,    const float* __restrict__ int_e,
    const int*   __restrict__ is_int,  float* __restrict__ out_rest)
{
    if (blockIdx.x >= AGG_BLOCKS) {
        const size_t NK    = (size_t)N_VERT * KNBR;
        const size_t total = 4 * NK + N_VERT;
        size_t t0 = (size_t)(blockIdx.x - AGG_BLOCKS) * 256 + threadIdx.x;
        for (size_t t = t0; t < total; t += (size_t)PASS_BLOCKS * 256) {
            float v;
            if      (t <     NK) v = (float)nh_idx[t];
            else if (t < 2 * NK) v = (float)int_idx[t - NK];
            else if (t < 3 * NK) v = nh_e[t - 2 * NK];
            else if (t < 4 * NK) v = int_e[t - 3 * NK];
            else                 v = (float)is_int[t - 4 * NK];
            out_rest[t] = v;
        }
        return;
    }

    const int lane = threadIdx.x & 63;
    const int wave = threadIdx.x >> 6;
    const int vg   = lane >> 4;
    const int fg   = lane & 15;
    const int i    = blockIdx.x * 16 + wave * 4 + vg;

    float a_i[8], a_n[8];
#pragma unroll
    for (int j = 0; j < 8; ++j) { a_i[j] = 0.f; a_n[j] = 0.f; }
    int ci = 0, cn = 0;

    // ---------------- interface edges ----------------
    {
        int sidx[KNBR]; float f[KNBR];
#pragma unroll
        for (int q = 0; q < 5; ++q) {
            int4   a = int_idx4[i * 5 + q];
            float4 e = int_e4[i * 5 + q];
            int   av[4] = {a.x, a.y, a.z, a.w};
            float ev[4] = {e.x, e.y, e.z, e.w};
#pragma unroll
            for (int j = 0; j < 4; ++j) {
                bool v = av[j] >= 0;
                ci += v;
                sidx[4 * q + j] = v ? av[j] : 0;
                f[4 * q + j]    = v ? ev[j] : 0.f;
            }
        }
        uint2 g[KNBR];
#pragma unroll
        for (int k = 0; k < KNBR; ++k)
            g[k] = *(const uint2*)(pay_i + (size_t)sidx[k] * 128 + fg * 8);
#pragma unroll
        for (int k = 0; k < KNBR; ++k) {
            float e = f[k];
            f32x2 p01 = __builtin_amdgcn_cvt_pk_f32_fp8((int)g[k].x, false);
            f32x2 p23 = __builtin_amdgcn_cvt_pk_f32_fp8((int)g[k].x, true);
            f32x2 p45 = __builtin_amdgcn_cvt_pk_f32_fp8((int)g[k].y, false);
            f32x2 p67 = __builtin_amdgcn_cvt_pk_f32_fp8((int)g[k].y, true);
            a_i[0] = fmaf(p01[0], e, a_i[0]);
            a_i[1] = fmaf(p01[1], e, a_i[1]);
            a_i[2] = fmaf(p23[0], e, a_i[2]);
            a_i[3] = fmaf(p23[1], e, a_i[3]);
            a_i[4] = fmaf(p45[0], e, a_i[4]);
            a_i[5] = fmaf(p45[1], e, a_i[5]);
            a_i[6] = fmaf(p67[0], e, a_i[6]);
            a_i[7] = fmaf(p67[1], e, a_i[7]);
        }
    }
    // ---------------- neighborhood edges ----------------
    {
        int sidx[KNBR]; float f[KNBR];
#pragma unroll
        for (int q = 0; q < 5; ++q) {
            int4   a = nh_idx4[i * 5 + q];
            float4 e = nh_e4[i * 5 + q];
            int   av[4] = {a.x, a.y, a.z, a.w};
            float ev[4] = {e.x, e.y, e.z, e.w};
#pragma unroll
            for (int j = 0; j < 4; ++j) {
                bool v = av[j] >= 0;
                cn += v;
                sidx[4 * q + j] = v ? av[j] : 0;
                f[4 * q + j]    = v ? ev[j] : 0.f;
            }
        }
        uint2 g[KNBR];
#pragma unroll
        for (int k = 0; k < KNBR; ++k)
            g[k] = *(const uint2*)(pay_n + (size_t)sidx[k] * 128 + fg * 8);
#pragma unroll
        for (int k = 0; k < KNBR; ++k) {
            float e = f[k];
            f32x2 p01 = __builtin_amdgcn_cvt_pk_f32_fp8((int)g[k].x, false);
            f32x2 p23 = __builtin_amdgcn_cvt_pk_f32_fp8((int)g[k].x, true);
            f32x2 p45 = __builtin_amdgcn_cvt_pk_f32_fp8((int)g[k].y, false);
            f32x2 p67 = __builtin_amdgcn_cvt_pk_f32_fp8((int)g[k].y, true);
            a_n[0] = fmaf(p01[0], e, a_n[0]);
            a_n[1] = fmaf(p01[1], e, a_n[1]);
            a_n[2] = fmaf(p23[0], e, a_n[2]);
            a_n[3] = fmaf(p23[1], e, a_n[3]);
            a_n[4] = fmaf(p45[0], e, a_n[4]);
            a_n[5] = fmaf(p45[1], e, a_n[5]);
            a_n[6] = fmaf(p67[0], e, a_n[6]);
            a_n[7] = fmaf(p67[1], e, a_n[7]);
        }
    }

    float ri = 1.f / (float)max(ci, 1);
    float rn = 1.f / (float)max(cn, 1);

    // zcp row (bias pre-added); un-permute via 8 dword stores
    uint4 zq = *(const uint4*)(zcp + (size_t)i * 128 + fg * 8);
    uint32 zd[4] = {zq.x, zq.y, zq.z, zq.w};
    float* zrow = z + (size_t)i * F + fg;
#pragma unroll
    for (int t = 0; t < 8; ++t) {
        uint32 dw = zd[t >> 1];
        float zc = __uint_as_float((t & 1) ? (dw & 0xffff0000u) : (dw << 16));
        float r  = zc + a_i[t] * ri + a_n[t] * rn;
        zrow[t * 16] = fmaxf(r, 0.f);      // filter t*16+fg
    }
}

extern "C" void kernel_launch(void* const* d_in, const int* in_sizes, int n_in,
                              void* d_out, int out_size, void* d_ws, size_t ws_size,
                              hipStream_t stream) {
    const float* vert    = (const float*)d_in[0];
    const int*   nh_idx  = (const int*)  d_in[1];
    const int*   int_idx = (const int*)  d_in[2];
    const float* nh_e    = (const float*)d_in[3];
    const float* int_e   = (const float*)d_in[4];
    const int*   is_int  = (const int*)  d_in[5];
    const float* Wc      = (const float*)d_in[6];
    const float* Wi      = (const float*)d_in[7];
    const float* Wn      = (const float*)d_in[8];
    const float* bv      = (const float*)d_in[9];

    float* z        = (float*)d_out;                     // [N, F]
    float* out_rest = z + (size_t)N_VERT * F;            // passthrough chunks

    uint8* pay_i = (uint8*)d_ws;                         // fp8 [N][128] permuted
    uint8* pay_n = pay_i + (size_t)N_VERT * F;           // fp8 [N][128] permuted
    ushort16* zcp = (ushort16*)(pay_n + (size_t)N_VERT * F); // bf16 [N][128] permuted (+bias)
    float* bvp   = (float*)(zcp + (size_t)N_VERT * F);   // f32 [128] permuted
    ushort16* Wt = (ushort16*)(bvp + F);                 // bf16 fragment-linear

    wconv_kernel<<<(3 * F * F + 255) / 256, 256, 0, stream>>>(Wc, Wi, Wn, bv, Wt, bvp);
    mfma_proj_kernel<<<NBLK, 256, 0, stream>>>(
        vert, Wt, bvp, zcp, pay_i, pay_n);
    agg_kernel<<<AGG_BLOCKS + PASS_BLOCKS, 256, 0, stream>>>(
        pay_i, pay_n, (const unsigned short*)zcp,
        (const int4*)int_idx, (const int4*)nh_idx,
        (const float4*)int_e, (const float4*)nh_e, z,
        nh_idx, int_idx, nh_e, int_e, is_int, out_rest);
}

// Round 14
// 71.336 us; speedup vs baseline: 1.2670x; 1.2670x over previous
//
#include <hip/hip_runtime.h>

#define N_VERT 50000
#define KNBR 20
#define F 128
#define NBLK 782        // ceil(50000/64)
#define AGG_BLOCKS 3125 // N_VERT/16
#define PASS_BLOCKS 1024

typedef unsigned int uint32;
typedef unsigned short ushort16;
typedef unsigned char uint8;
typedef __attribute__((ext_vector_type(8))) short bf16x8;
typedef __attribute__((ext_vector_type(4))) float f32x4;
typedef __attribute__((ext_vector_type(2))) float f32x2;

__device__ __forceinline__ uint32 f2bf_bits(float x) {
    uint32 u = __float_as_uint(x);
    u += 0x7fff + ((u >> 16) & 1);        // round-to-nearest-even
    return u >> 16;
}

// ---------------------------------------------------------------------------
// Kernel W: weights -> bf16 fragment-linear Wt + permuted bias bvp.
// Permuted column order: c' = lr*8 + nt  <->  filter nt*16 + lr.
// ---------------------------------------------------------------------------
__global__ __launch_bounds__(256) void wconv_kernel(
    const float* __restrict__ Wc, const float* __restrict__ Wi,
    const float* __restrict__ Wn, const float* __restrict__ bv,
    ushort16* __restrict__ Wt, float* __restrict__ bvp)
{
    int t = blockIdx.x * 256 + threadIdx.x;
    if (blockIdx.x == 0 && threadIdx.x < 128) {
        int c = threadIdx.x;                    // c' = lr*8+nt
        bvp[c] = bv[(c & 7) * 16 + (c >> 3)];   // filter nt*16+lr
    }
    if (t >= 3 * F * F) return;
    int w    = t >> 14;
    int r    = t & 16383;
    int kk   = r >> 12;
    int r2   = r & 4095;
    int nt   = r2 >> 9;
    int r3   = r2 & 511;
    int lane = r3 >> 3;
    int e    = r3 & 7;
    int k = kk * 32 + (lane >> 4) * 8 + e;
    int n = nt * 16 + (lane & 15);
    const float* W = (w == 0) ? Wc : ((w == 1) ? Wi : Wn);
    Wt[t] = (ushort16)f2bf_bits(W[k * F + n]);
}

// ---------------------------------------------------------------------------
// Kernel A: FUSED projections, SEQUENTIAL-w phases (R12 structure: vert read
// once, one 8-acc set live per phase, no LDS). Change vs R12: no min-waves
// cap, and each phase loads ALL 32 B-fragments into registers (bfr[32], 128
// VGPR, static indices) before the MFMA burst -> 32 loads in flight per wave
// (max MLP; latency hidden by ILP instead of the occupancy R12's cap gave).
// Register-direct permuted stores (c' = lr*8+nt):
//   w==0 -> zcp bf16[N][128] with bias pre-added
//   w==1/2 -> fp8 e4m3 [N][128] via HW cvt_pk_fp8_f32
// ---------------------------------------------------------------------------
__global__ __launch_bounds__(256) void mfma_proj_kernel(
    const float*    __restrict__ vert,
    const ushort16* __restrict__ Wt,
    const float*    __restrict__ bvp,
    ushort16* __restrict__ zcp,
    uint8* __restrict__ pay_i,
    uint8* __restrict__ pay_n)
{
    const int wave = threadIdx.x >> 6;
    const int lane = threadIdx.x & 63;
    const int lr   = lane & 15;
    const int lk   = lane >> 4;
    const int rb   = (blockIdx.x * 4 + wave) * 16;

    // ---- A fragments: V rows read ONCE, converted inline (clamped tail) ----
    int rowA = rb + lr; if (rowA > N_VERT - 1) rowA = N_VERT - 1;
    const float* vrow = vert + (size_t)rowA * F;
    bf16x8 afrag[4];
#pragma unroll
    for (int kk = 0; kk < 4; ++kk) {
        const float* p = vrow + kk * 32 + lk * 8;
        f32x4 lo = *(const f32x4*)p;
        f32x4 hi = *(const f32x4*)(p + 4);
#pragma unroll
        for (int j = 0; j < 4; ++j) {
            afrag[kk][j]     = (short)f2bf_bits(lo[j]);
            afrag[kk][4 + j] = (short)f2bf_bits(hi[j]);
        }
    }

    const bf16x8* gW = (const bf16x8*)Wt + lane;   // lane's fragment base (x64 stride)

#pragma unroll
    for (int w = 0; w < 3; ++w) {
        // ---- load ALL 32 B-fragments of this w into registers (max MLP) ----
        bf16x8 bfr[32];
#pragma unroll
        for (int t = 0; t < 32; ++t)
            bfr[t] = gW[(size_t)(w * 32 + t) * 64];

        f32x4 acc[8];
#pragma unroll
        for (int nt = 0; nt < 8; ++nt) acc[nt] = (f32x4)(0.f);

#pragma unroll
        for (int kk = 0; kk < 4; ++kk)
#pragma unroll
            for (int nt = 0; nt < 8; ++nt)
                acc[nt] = __builtin_amdgcn_mfma_f32_16x16x32_bf16(
                    afrag[kk], bfr[kk * 8 + nt], acc[nt], 0, 0, 0);

        if (w == 0) {
            // bias pre-add (filter nt*16+lr -> bvp[lr*8+nt]), bf16 permuted store
            f32x4 bb0 = *(const f32x4*)(bvp + lr * 8);
            f32x4 bb1 = *(const f32x4*)(bvp + lr * 8 + 4);
            float bbv[8] = {bb0[0], bb0[1], bb0[2], bb0[3],
                            bb1[0], bb1[1], bb1[2], bb1[3]};
#pragma unroll
            for (int j = 0; j < 4; ++j) {
                int row = rb + lk * 4 + j;
                if (row >= N_VERT) continue;
                uint32 d[4];
#pragma unroll
                for (int p = 0; p < 4; ++p)
                    d[p] = f2bf_bits(acc[2 * p][j] + bbv[2 * p]) |
                           (f2bf_bits(acc[2 * p + 1][j] + bbv[2 * p + 1]) << 16);
                *(uint4*)((uint8*)zcp + (size_t)row * 256 + lr * 16) =
                    make_uint4(d[0], d[1], d[2], d[3]);
            }
        } else {
            uint8* pay = (w == 1) ? pay_i : pay_n;
#pragma unroll
            for (int j = 0; j < 4; ++j) {
                int row = rb + lk * 4 + j;
                if (row >= N_VERT) continue;
                uint32 lo, hi;
                lo = __builtin_amdgcn_cvt_pk_fp8_f32(acc[0][j], acc[1][j], 0, false);
                lo = __builtin_amdgcn_cvt_pk_fp8_f32(acc[2][j], acc[3][j], lo, true);
                hi = __builtin_amdgcn_cvt_pk_fp8_f32(acc[4][j], acc[5][j], 0, false);
                hi = __builtin_amdgcn_cvt_pk_fp8_f32(acc[6][j], acc[7][j], hi, true);
                *(uint2*)(pay + (size_t)row * 128 + lr * 8) = make_uint2(lo, hi);
            }
        }
    }
}

// ---------------------------------------------------------------------------
// Kernel B: gather-aggregate (fp8 payload) + FOLDED passthrough. (R12 exact)
// ---------------------------------------------------------------------------
__global__ __launch_bounds__(256) void agg_kernel(
    const uint8*  __restrict__ pay_i,
    const uint8*  __restrict__ pay_n,
    const unsigned short* __restrict__ zcp,
    const int4*   __restrict__ int_idx4,
    const int4*   __restrict__ nh_idx4,
    const float4* __restrict__ int_e4,
    const float4* __restrict__ nh_e4,
    float* __restrict__ z,
    const int*   __restrict__ nh_idx,  const int*   __restrict__ int_idx,
    const float* __restrict__ nh_e,    const float* __restrict__ int_e,
    const int*   __restrict__ is_int,  float* __restrict__ out_rest)
{
    if (blockIdx.x >= AGG_BLOCKS) {
        const size_t NK    = (size_t)N_VERT * KNBR;
        const size_t total = 4 * NK + N_VERT;
        size_t t0 = (size_t)(blockIdx.x - AGG_BLOCKS) * 256 + threadIdx.x;
        for (size_t t = t0; t < total; t += (size_t)PASS_BLOCKS * 256) {
            float v;
            if      (t <     NK) v = (float)nh_idx[t];
            else if (t < 2 * NK) v = (float)int_idx[t - NK];
            else if (t < 3 * NK) v = nh_e[t - 2 * NK];
            else if (t < 4 * NK) v = int_e[t - 3 * NK];
            else                 v = (float)is_int[t - 4 * NK];
            out_rest[t] = v;
        }
        return;
    }

    const int lane = threadIdx.x & 63;
    const int wave = threadIdx.x >> 6;
    const int vg   = lane >> 4;
    const int fg   = lane & 15;
    const int i    = blockIdx.x * 16 + wave * 4 + vg;

    float a_i[8], a_n[8];
#pragma unroll
    for (int j = 0; j < 8; ++j) { a_i[j] = 0.f; a_n[j] = 0.f; }
    int ci = 0, cn = 0;

    // ---------------- interface edges ----------------
    {
        int sidx[KNBR]; float f[KNBR];
#pragma unroll
        for (int q = 0; q < 5; ++q) {
            int4   a = int_idx4[i * 5 + q];
            float4 e = int_e4[i * 5 + q];
            int   av[4] = {a.x, a.y, a.z, a.w};
            float ev[4] = {e.x, e.y, e.z, e.w};
#pragma unroll
            for (int j = 0; j < 4; ++j) {
                bool v = av[j] >= 0;
                ci += v;
                sidx[4 * q + j] = v ? av[j] : 0;
                f[4 * q + j]    = v ? ev[j] : 0.f;
            }
        }
        uint2 g[KNBR];
#pragma unroll
        for (int k = 0; k < KNBR; ++k)
            g[k] = *(const uint2*)(pay_i + (size_t)sidx[k] * 128 + fg * 8);
#pragma unroll
        for (int k = 0; k < KNBR; ++k) {
            float e = f[k];
            f32x2 p01 = __builtin_amdgcn_cvt_pk_f32_fp8((int)g[k].x, false);
            f32x2 p23 = __builtin_amdgcn_cvt_pk_f32_fp8((int)g[k].x, true);
            f32x2 p45 = __builtin_amdgcn_cvt_pk_f32_fp8((int)g[k].y, false);
            f32x2 p67 = __builtin_amdgcn_cvt_pk_f32_fp8((int)g[k].y, true);
            a_i[0] = fmaf(p01[0], e, a_i[0]);
            a_i[1] = fmaf(p01[1], e, a_i[1]);
            a_i[2] = fmaf(p23[0], e, a_i[2]);
            a_i[3] = fmaf(p23[1], e, a_i[3]);
            a_i[4] = fmaf(p45[0], e, a_i[4]);
            a_i[5] = fmaf(p45[1], e, a_i[5]);
            a_i[6] = fmaf(p67[0], e, a_i[6]);
            a_i[7] = fmaf(p67[1], e, a_i[7]);
        }
    }
    // ---------------- neighborhood edges ----------------
    {
        int sidx[KNBR]; float f[KNBR];
#pragma unroll
        for (int q = 0; q < 5; ++q) {
            int4   a = nh_idx4[i * 5 + q];
            float4 e = nh_e4[i * 5 + q];
            int   av[4] = {a.x, a.y, a.z, a.w};
            float ev[4] = {e.x, e.y, e.z, e.w};
#pragma unroll
            for (int j = 0; j < 4; ++j) {
                bool v = av[j] >= 0;
                cn += v;
                sidx[4 * q + j] = v ? av[j] : 0;
                f[4 * q + j]    = v ? ev[j] : 0.f;
            }
        }
        uint2 g[KNBR];
#pragma unroll
        for (int k = 0; k < KNBR; ++k)
            g[k] = *(const uint2*)(pay_n + (size_t)sidx[k] * 128 + fg * 8);
#pragma unroll
        for (int k = 0; k < KNBR; ++k) {
            float e = f[k];
            f32x2 p01 = __builtin_amdgcn_cvt_pk_f32_fp8((int)g[k].x, false);
            f32x2 p23 = __builtin_amdgcn_cvt_pk_f32_fp8((int)g[k].x, true);
            f32x2 p45 = __builtin_amdgcn_cvt_pk_f32_fp8((int)g[k].y, false);
            f32x2 p67 = __builtin_amdgcn_cvt_pk_f32_fp8((int)g[k].y, true);
            a_n[0] = fmaf(p01[0], e, a_n[0]);
            a_n[1] = fmaf(p01[1], e, a_n[1]);
            a_n[2] = fmaf(p23[0], e, a_n[2]);
            a_n[3] = fmaf(p23[1], e, a_n[3]);
            a_n[4] = fmaf(p45[0], e, a_n[4]);
            a_n[5] = fmaf(p45[1], e, a_n[5]);
            a_n[6] = fmaf(p67[0], e, a_n[6]);
            a_n[7] = fmaf(p67[1], e, a_n[7]);
        }
    }

    float ri = 1.f / (float)max(ci, 1);
    float rn = 1.f / (float)max(cn, 1);

    // zcp row (bias pre-added); un-permute via 8 dword stores
    uint4 zq = *(const uint4*)(zcp + (size_t)i * 128 + fg * 8);
    uint32 zd[4] = {zq.x, zq.y, zq.z, zq.w};
    float* zrow = z + (size_t)i * F + fg;
#pragma unroll
    for (int t = 0; t < 8; ++t) {
        uint32 dw = zd[t >> 1];
        float zc = __uint_as_float((t & 1) ? (dw & 0xffff0000u) : (dw << 16));
        float r  = zc + a_i[t] * ri + a_n[t] * rn;
        zrow[t * 16] = fmaxf(r, 0.f);      // filter t*16+fg
    }
}

extern "C" void kernel_launch(void* const* d_in, const int* in_sizes, int n_in,
                              void* d_out, int out_size, void* d_ws, size_t ws_size,
                              hipStream_t stream) {
    const float* vert    = (const float*)d_in[0];
    const int*   nh_idx  = (const int*)  d_in[1];
    const int*   int_idx = (const int*)  d_in[2];
    const float* nh_e    = (const float*)d_in[3];
    const float* int_e   = (const float*)d_in[4];
    const int*   is_int  = (const int*)  d_in[5];
    const float* Wc      = (const float*)d_in[6];
    const float* Wi      = (const float*)d_in[7];
    const float* Wn      = (const float*)d_in[8];
    const float* bv      = (const float*)d_in[9];

    float* z        = (float*)d_out;                     // [N, F]
    float* out_rest = z + (size_t)N_VERT * F;            // passthrough chunks

    uint8* pay_i = (uint8*)d_ws;                         // fp8 [N][128] permuted
    uint8* pay_n = pay_i + (size_t)N_VERT * F;           // fp8 [N][128] permuted
    ushort16* zcp = (ushort16*)(pay_n + (size_t)N_VERT * F); // bf16 [N][128] permuted (+bias)
    float* bvp   = (float*)(zcp + (size_t)N_VERT * F);   // f32 [128] permuted
    ushort16* Wt = (ushort16*)(bvp + F);                 // bf16 fragment-linear

    wconv_kernel<<<(3 * F * F + 255) / 256, 256, 0, stream>>>(Wc, Wi, Wn, bv, Wt, bvp);
    mfma_proj_kernel<<<NBLK, 256, 0, stream>>>(
        vert, Wt, bvp, zcp, pay_i, pay_n);
    agg_kernel<<<AGG_BLOCKS + PASS_BLOCKS, 256, 0, stream>>>(
        pay_i, pay_n, (const unsigned short*)zcp,
        (const int4*)int_idx, (const int4*)nh_idx,
        (const float4*)int_e, (const float4*)nh_e, z,
        nh_idx, int_idx, nh_e, int_e, is_int, out_rest);
}

// Round 15
// 69.781 us; speedup vs baseline: 1.2952x; 1.0223x over previous
//
#include <hip/hip_runtime.h>

#define N_VERT 50000
#define KNBR 20
#define F 128
#define NBLK 782        // ceil(50000/64)
#define AGG_BLOCKS 3125 // N_VERT/16
#define PASS_BLOCKS 1024

typedef unsigned int uint32;
typedef unsigned short ushort16;
typedef unsigned char uint8;
typedef __attribute__((ext_vector_type(8))) short bf16x8;
typedef __attribute__((ext_vector_type(4))) float f32x4;
typedef __attribute__((ext_vector_type(2))) float f32x2;

__device__ __forceinline__ uint32 f2bf_bits(float x) {
    uint32 u = __float_as_uint(x);
    u += 0x7fff + ((u >> 16) & 1);        // round-to-nearest-even
    return u >> 16;
}

// ---------------------------------------------------------------------------
// Kernel W: weights -> bf16 fragment-linear Wt + permuted bias bvp.
// Permuted column order: c' = lr*8 + nt  <->  filter nt*16 + lr.
// ---------------------------------------------------------------------------
__global__ __launch_bounds__(256) void wconv_kernel(
    const float* __restrict__ Wc, const float* __restrict__ Wi,
    const float* __restrict__ Wn, const float* __restrict__ bv,
    ushort16* __restrict__ Wt, float* __restrict__ bvp)
{
    int t = blockIdx.x * 256 + threadIdx.x;
    if (blockIdx.x == 0 && threadIdx.x < 128) {
        int c = threadIdx.x;                    // c' = lr*8+nt
        bvp[c] = bv[(c & 7) * 16 + (c >> 3)];   // filter nt*16+lr
    }
    if (t >= 3 * F * F) return;
    int w    = t >> 14;
    int r    = t & 16383;
    int kk   = r >> 12;
    int r2   = r & 4095;
    int nt   = r2 >> 9;
    int r3   = r2 & 511;
    int lane = r3 >> 3;
    int e    = r3 & 7;
    int k = kk * 32 + (lane >> 4) * 8 + e;
    int n = nt * 16 + (lane & 15);
    const float* W = (w == 0) ? Wc : ((w == 1) ? Wi : Wn);
    Wt[t] = (ushort16)f2bf_bits(W[k * F + n]);
}

// ---------------------------------------------------------------------------
// Kernel A: FUSED projections (R14 body) + FOLDED passthrough.
// Blocks < NBLK: sequential-w MFMA proj (vert once, bfr[32] max-MLP, no LDS).
// Blocks >= NBLK: grid-stride passthrough — streams through proj's idle
// memory pipes (proj is ~90% latency-stalled: MfmaUtil 4%, VALUBusy 5%).
// ---------------------------------------------------------------------------
__global__ __launch_bounds__(256) void mfma_proj_kernel(
    const float*    __restrict__ vert,
    const ushort16* __restrict__ Wt,
    const float*    __restrict__ bvp,
    ushort16* __restrict__ zcp,
    uint8* __restrict__ pay_i,
    uint8* __restrict__ pay_n,
    const int*   __restrict__ nh_idx,  const int*   __restrict__ int_idx,
    const float* __restrict__ nh_e,    const float* __restrict__ int_e,
    const int*   __restrict__ is_int,  float* __restrict__ out_rest)
{
    if (blockIdx.x >= NBLK) {
        // ---------------- passthrough section ----------------
        const size_t NK    = (size_t)N_VERT * KNBR;
        const size_t total = 4 * NK + N_VERT;
        size_t t0 = (size_t)(blockIdx.x - NBLK) * 256 + threadIdx.x;
        for (size_t t = t0; t < total; t += (size_t)PASS_BLOCKS * 256) {
            float v;
            if      (t <     NK) v = (float)nh_idx[t];
            else if (t < 2 * NK) v = (float)int_idx[t - NK];
            else if (t < 3 * NK) v = nh_e[t - 2 * NK];
            else if (t < 4 * NK) v = int_e[t - 3 * NK];
            else                 v = (float)is_int[t - 4 * NK];
            out_rest[t] = v;
        }
        return;
    }

    const int wave = threadIdx.x >> 6;
    const int lane = threadIdx.x & 63;
    const int lr   = lane & 15;
    const int lk   = lane >> 4;
    const int rb   = (blockIdx.x * 4 + wave) * 16;

    // ---- A fragments: V rows read ONCE, converted inline (clamped tail) ----
    int rowA = rb + lr; if (rowA > N_VERT - 1) rowA = N_VERT - 1;
    const float* vrow = vert + (size_t)rowA * F;
    bf16x8 afrag[4];
#pragma unroll
    for (int kk = 0; kk < 4; ++kk) {
        const float* p = vrow + kk * 32 + lk * 8;
        f32x4 lo = *(const f32x4*)p;
        f32x4 hi = *(const f32x4*)(p + 4);
#pragma unroll
        for (int j = 0; j < 4; ++j) {
            afrag[kk][j]     = (short)f2bf_bits(lo[j]);
            afrag[kk][4 + j] = (short)f2bf_bits(hi[j]);
        }
    }

    const bf16x8* gW = (const bf16x8*)Wt + lane;   // lane's fragment base

#pragma unroll
    for (int w = 0; w < 3; ++w) {
        // ---- load ALL 32 B-fragments of this w into registers (max MLP) ----
        bf16x8 bfr[32];
#pragma unroll
        for (int t = 0; t < 32; ++t)
            bfr[t] = gW[(size_t)(w * 32 + t) * 64];

        f32x4 acc[8];
#pragma unroll
        for (int nt = 0; nt < 8; ++nt) acc[nt] = (f32x4)(0.f);

#pragma unroll
        for (int kk = 0; kk < 4; ++kk)
#pragma unroll
            for (int nt = 0; nt < 8; ++nt)
                acc[nt] = __builtin_amdgcn_mfma_f32_16x16x32_bf16(
                    afrag[kk], bfr[kk * 8 + nt], acc[nt], 0, 0, 0);

        if (w == 0) {
            // bias pre-add (filter nt*16+lr -> bvp[lr*8+nt]), bf16 permuted store
            f32x4 bb0 = *(const f32x4*)(bvp + lr * 8);
            f32x4 bb1 = *(const f32x4*)(bvp + lr * 8 + 4);
            float bbv[8] = {bb0[0], bb0[1], bb0[2], bb0[3],
                            bb1[0], bb1[1], bb1[2], bb1[3]};
#pragma unroll
            for (int j = 0; j < 4; ++j) {
                int row = rb + lk * 4 + j;
                if (row >= N_VERT) continue;
                uint32 d[4];
#pragma unroll
                for (int p = 0; p < 4; ++p)
                    d[p] = f2bf_bits(acc[2 * p][j] + bbv[2 * p]) |
                           (f2bf_bits(acc[2 * p + 1][j] + bbv[2 * p + 1]) << 16);
                *(uint4*)((uint8*)zcp + (size_t)row * 256 + lr * 16) =
                    make_uint4(d[0], d[1], d[2], d[3]);
            }
        } else {
            uint8* pay = (w == 1) ? pay_i : pay_n;
#pragma unroll
            for (int j = 0; j < 4; ++j) {
                int row = rb + lk * 4 + j;
                if (row >= N_VERT) continue;
                uint32 lo, hi;
                lo = __builtin_amdgcn_cvt_pk_fp8_f32(acc[0][j], acc[1][j], 0, false);
                lo = __builtin_amdgcn_cvt_pk_fp8_f32(acc[2][j], acc[3][j], lo, true);
                hi = __builtin_amdgcn_cvt_pk_fp8_f32(acc[4][j], acc[5][j], 0, false);
                hi = __builtin_amdgcn_cvt_pk_fp8_f32(acc[6][j], acc[7][j], hi, true);
                *(uint2*)(pay + (size_t)row * 128 + lr * 8) = make_uint2(lo, hi);
            }
        }
    }
}

// ---------------------------------------------------------------------------
// Kernel B: gather-aggregate on permuted fp8 payload. EXACT R11 config
// (3125 blocks, no pass branch) — proven 40.0 us.
// ---------------------------------------------------------------------------
__global__ __launch_bounds__(256) void agg_kernel(
    const uint8*  __restrict__ pay_i,
    const uint8*  __restrict__ pay_n,
    const unsigned short* __restrict__ zcp,
    const int4*   __restrict__ int_idx4,
    const int4*   __restrict__ nh_idx4,
    const float4* __restrict__ int_e4,
    const float4* __restrict__ nh_e4,
    float* __restrict__ z)
{
    const int lane = threadIdx.x & 63;
    const int wave = threadIdx.x >> 6;
    const int vg   = lane >> 4;
    const int fg   = lane & 15;
    const int i    = blockIdx.x * 16 + wave * 4 + vg;

    float a_i[8], a_n[8];
#pragma unroll
    for (int j = 0; j < 8; ++j) { a_i[j] = 0.f; a_n[j] = 0.f; }
    int ci = 0, cn = 0;

    // ---------------- interface edges ----------------
    {
        int sidx[KNBR]; float f[KNBR];
#pragma unroll
        for (int q = 0; q < 5; ++q) {
            int4   a = int_idx4[i * 5 + q];
            float4 e = int_e4[i * 5 + q];
            int   av[4] = {a.x, a.y, a.z, a.w};
            float ev[4] = {e.x, e.y, e.z, e.w};
#pragma unroll
            for (int j = 0; j < 4; ++j) {
                bool v = av[j] >= 0;
                ci += v;
                sidx[4 * q + j] = v ? av[j] : 0;
                f[4 * q + j]    = v ? ev[j] : 0.f;
            }
        }
        uint2 g[KNBR];
#pragma unroll
        for (int k = 0; k < KNBR; ++k)
            g[k] = *(const uint2*)(pay_i + (size_t)sidx[k] * 128 + fg * 8);
#pragma unroll
        for (int k = 0; k < KNBR; ++k) {
            float e = f[k];
            f32x2 p01 = __builtin_amdgcn_cvt_pk_f32_fp8((int)g[k].x, false);
            f32x2 p23 = __builtin_amdgcn_cvt_pk_f32_fp8((int)g[k].x, true);
            f32x2 p45 = __builtin_amdgcn_cvt_pk_f32_fp8((int)g[k].y, false);
            f32x2 p67 = __builtin_amdgcn_cvt_pk_f32_fp8((int)g[k].y, true);
            a_i[0] = fmaf(p01[0], e, a_i[0]);
            a_i[1] = fmaf(p01[1], e, a_i[1]);
            a_i[2] = fmaf(p23[0], e, a_i[2]);
            a_i[3] = fmaf(p23[1], e, a_i[3]);
            a_i[4] = fmaf(p45[0], e, a_i[4]);
            a_i[5] = fmaf(p45[1], e, a_i[5]);
            a_i[6] = fmaf(p67[0], e, a_i[6]);
            a_i[7] = fmaf(p67[1], e, a_i[7]);
        }
    }
    // ---------------- neighborhood edges ----------------
    {
        int sidx[KNBR]; float f[KNBR];
#pragma unroll
        for (int q = 0; q < 5; ++q) {
            int4   a = nh_idx4[i * 5 + q];
            float4 e = nh_e4[i * 5 + q];
            int   av[4] = {a.x, a.y, a.z, a.w};
            float ev[4] = {e.x, e.y, e.z, e.w};
#pragma unroll
            for (int j = 0; j < 4; ++j) {
                bool v = av[j] >= 0;
                cn += v;
                sidx[4 * q + j] = v ? av[j] : 0;
                f[4 * q + j]    = v ? ev[j] : 0.f;
            }
        }
        uint2 g[KNBR];
#pragma unroll
        for (int k = 0; k < KNBR; ++k)
            g[k] = *(const uint2*)(pay_n + (size_t)sidx[k] * 128 + fg * 8);
#pragma unroll
        for (int k = 0; k < KNBR; ++k) {
            float e = f[k];
            f32x2 p01 = __builtin_amdgcn_cvt_pk_f32_fp8((int)g[k].x, false);
            f32x2 p23 = __builtin_amdgcn_cvt_pk_f32_fp8((int)g[k].x, true);
            f32x2 p45 = __builtin_amdgcn_cvt_pk_f32_fp8((int)g[k].y, false);
            f32x2 p67 = __builtin_amdgcn_cvt_pk_f32_fp8((int)g[k].y, true);
            a_n[0] = fmaf(p01[0], e, a_n[0]);
            a_n[1] = fmaf(p01[1], e, a_n[1]);
            a_n[2] = fmaf(p23[0], e, a_n[2]);
            a_n[3] = fmaf(p23[1], e, a_n[3]);
            a_n[4] = fmaf(p45[0], e, a_n[4]);
            a_n[5] = fmaf(p45[1], e, a_n[5]);
            a_n[6] = fmaf(p67[0], e, a_n[6]);
            a_n[7] = fmaf(p67[1], e, a_n[7]);
        }
    }

    float ri = 1.f / (float)max(ci, 1);
    float rn = 1.f / (float)max(cn, 1);

    // zcp row (bias pre-added); un-permute via 8 dword stores
    uint4 zq = *(const uint4*)(zcp + (size_t)i * 128 + fg * 8);
    uint32 zd[4] = {zq.x, zq.y, zq.z, zq.w};
    float* zrow = z + (size_t)i * F + fg;
#pragma unroll
    for (int t = 0; t < 8; ++t) {
        uint32 dw = zd[t >> 1];
        float zc = __uint_as_float((t & 1) ? (dw & 0xffff0000u) : (dw << 16));
        float r  = zc + a_i[t] * ri + a_n[t] * rn;
        zrow[t * 16] = fmaxf(r, 0.f);      // filter t*16+fg
    }
}

extern "C" void kernel_launch(void* const* d_in, const int* in_sizes, int n_in,
                              void* d_out, int out_size, void* d_ws, size_t ws_size,
                              hipStream_t stream) {
    const float* vert    = (const float*)d_in[0];
    const int*   nh_idx  = (const int*)  d_in[1];
    const int*   int_idx = (const int*)  d_in[2];
    const float* nh_e    = (const float*)d_in[3];
    const float* int_e   = (const float*)d_in[4];
    const int*   is_int  = (const int*)  d_in[5];
    const float* Wc      = (const float*)d_in[6];
    const float* Wi      = (const float*)d_in[7];
    const float* Wn      = (const float*)d_in[8];
    const float* bv      = (const float*)d_in[9];

    float* z        = (float*)d_out;                     // [N, F]
    float* out_rest = z + (size_t)N_VERT * F;            // passthrough chunks

    uint8* pay_i = (uint8*)d_ws;                         // fp8 [N][128] permuted
    uint8* pay_n = pay_i + (size_t)N_VERT * F;           // fp8 [N][128] permuted
    ushort16* zcp = (ushort16*)(pay_n + (size_t)N_VERT * F); // bf16 [N][128] permuted (+bias)
    float* bvp   = (float*)(zcp + (size_t)N_VERT * F);   // f32 [128] permuted
    ushort16* Wt = (ushort16*)(bvp + F);                 // bf16 fragment-linear

    wconv_kernel<<<(3 * F * F + 255) / 256, 256, 0, stream>>>(Wc, Wi, Wn, bv, Wt, bvp);
    mfma_proj_kernel<<<NBLK + PASS_BLOCKS, 256, 0, stream>>>(
        vert, Wt, bvp, zcp, pay_i, pay_n,
        nh_idx, int_idx, nh_e, int_e, is_int, out_rest);
    agg_kernel<<<AGG_BLOCKS, 256, 0, stream>>>(
        pay_i, pay_n, (const unsigned short*)zcp,
        (const int4*)int_idx, (const int4*)nh_idx,
        (const float4*)int_e, (const float4*)nh_e, z);
}

// Round 16
// 69.594 us; speedup vs baseline: 1.2987x; 1.0027x over previous
//
#include <hip/hip_runtime.h>

#define N_VERT 50000
#define KNBR 20
#define F 128
#define NBLK 782        // ceil(50000/64)
#define AGG_BLOCKS 3125 // N_VERT/16
#define PASS_BLOCKS 1024

typedef unsigned int uint32;
typedef unsigned short ushort16;
typedef unsigned char uint8;
typedef __attribute__((ext_vector_type(8))) short bf16x8;
typedef __attribute__((ext_vector_type(4))) float f32x4;
typedef __attribute__((ext_vector_type(2))) float f32x2;

__device__ __forceinline__ uint32 f2bf_bits(float x) {
    uint32 u = __float_as_uint(x);
    u += 0x7fff + ((u >> 16) & 1);        // round-to-nearest-even
    return u >> 16;
}

// ---------------------------------------------------------------------------
// Kernel W: weights -> bf16 fragment-linear Wt + permuted bias bvp.
// Permuted column order: c' = lr*8 + nt  <->  filter nt*16 + lr.
// ---------------------------------------------------------------------------
__global__ __launch_bounds__(256) void wconv_kernel(
    const float* __restrict__ Wc, const float* __restrict__ Wi,
    const float* __restrict__ Wn, const float* __restrict__ bv,
    ushort16* __restrict__ Wt, float* __restrict__ bvp)
{
    int t = blockIdx.x * 256 + threadIdx.x;
    if (blockIdx.x == 0 && threadIdx.x < 128) {
        int c = threadIdx.x;                    // c' = lr*8+nt
        bvp[c] = bv[(c & 7) * 16 + (c >> 3)];   // filter nt*16+lr
    }
    if (t >= 3 * F * F) return;
    int w    = t >> 14;
    int r    = t & 16383;
    int kk   = r >> 12;
    int r2   = r & 4095;
    int nt   = r2 >> 9;
    int r3   = r2 & 511;
    int lane = r3 >> 3;
    int e    = r3 & 7;
    int k = kk * 32 + (lane >> 4) * 8 + e;
    int n = nt * 16 + (lane & 15);
    const float* W = (w == 0) ? Wc : ((w == 1) ? Wi : Wn);
    Wt[t] = (ushort16)f2bf_bits(W[k * F + n]);
}

// ---------------------------------------------------------------------------
// Kernel A: FUSED projections + FOLDED passthrough (R15 structure).
// Change vs R15: __launch_bounds__(256,2) (128-VGPR budget) + EXPLICIT
// 2-stage software pipeline at kk granularity: prefetch kk+1's 8 B-fragments
// (nxt[8], 32 VGPR) while MFMAing cur[8]. Live ~95 VGPR: big enough that the
// allocator keeps the batches hoisted (R15's VGPR=56 flattened them), small
// enough not to spill (R13 lesson).
// ---------------------------------------------------------------------------
__global__ __launch_bounds__(256, 2) void mfma_proj_kernel(
    const float*    __restrict__ vert,
    const ushort16* __restrict__ Wt,
    const float*    __restrict__ bvp,
    ushort16* __restrict__ zcp,
    uint8* __restrict__ pay_i,
    uint8* __restrict__ pay_n,
    const int*   __restrict__ nh_idx,  const int*   __restrict__ int_idx,
    const float* __restrict__ nh_e,    const float* __restrict__ int_e,
    const int*   __restrict__ is_int,  float* __restrict__ out_rest)
{
    if (blockIdx.x >= NBLK) {
        // ---------------- passthrough section ----------------
        const size_t NK    = (size_t)N_VERT * KNBR;
        const size_t total = 4 * NK + N_VERT;
        size_t t0 = (size_t)(blockIdx.x - NBLK) * 256 + threadIdx.x;
        for (size_t t = t0; t < total; t += (size_t)PASS_BLOCKS * 256) {
            float v;
            if      (t <     NK) v = (float)nh_idx[t];
            else if (t < 2 * NK) v = (float)int_idx[t - NK];
            else if (t < 3 * NK) v = nh_e[t - 2 * NK];
            else if (t < 4 * NK) v = int_e[t - 3 * NK];
            else                 v = (float)is_int[t - 4 * NK];
            out_rest[t] = v;
        }
        return;
    }

    const int wave = threadIdx.x >> 6;
    const int lane = threadIdx.x & 63;
    const int lr   = lane & 15;
    const int lk   = lane >> 4;
    const int rb   = (blockIdx.x * 4 + wave) * 16;

    // ---- A fragments: V rows read ONCE, converted inline (clamped tail) ----
    int rowA = rb + lr; if (rowA > N_VERT - 1) rowA = N_VERT - 1;
    const float* vrow = vert + (size_t)rowA * F;
    bf16x8 afrag[4];
#pragma unroll
    for (int kk = 0; kk < 4; ++kk) {
        const float* p = vrow + kk * 32 + lk * 8;
        f32x4 lo = *(const f32x4*)p;
        f32x4 hi = *(const f32x4*)(p + 4);
#pragma unroll
        for (int j = 0; j < 4; ++j) {
            afrag[kk][j]     = (short)f2bf_bits(lo[j]);
            afrag[kk][4 + j] = (short)f2bf_bits(hi[j]);
        }
    }

    const bf16x8* gW = (const bf16x8*)Wt + lane;   // lane's fragment base

    // prologue: prefetch phase 0 (w=0, kk=0)
    bf16x8 cur[8], nxt[8];
#pragma unroll
    for (int nt = 0; nt < 8; ++nt)
        cur[nt] = gW[(size_t)nt * 64];

#pragma unroll
    for (int w = 0; w < 3; ++w) {
        f32x4 acc[8];
#pragma unroll
        for (int nt = 0; nt < 8; ++nt) acc[nt] = (f32x4)(0.f);

#pragma unroll
        for (int kk = 0; kk < 4; ++kk) {
            // prefetch next phase's 8 fragments (wraps to w+1's kk=0)
            int np = w * 4 + kk + 1;
            if (np < 12) {
#pragma unroll
                for (int nt = 0; nt < 8; ++nt)
                    nxt[nt] = gW[(size_t)(np * 8 + nt) * 64];
            }
            // MFMA burst on current phase
#pragma unroll
            for (int nt = 0; nt < 8; ++nt)
                acc[nt] = __builtin_amdgcn_mfma_f32_16x16x32_bf16(
                    afrag[kk], cur[nt], acc[nt], 0, 0, 0);
            // rotate
#pragma unroll
            for (int nt = 0; nt < 8; ++nt) cur[nt] = nxt[nt];
        }

        if (w == 0) {
            // bias pre-add (filter nt*16+lr -> bvp[lr*8+nt]), bf16 permuted store
            f32x4 bb0 = *(const f32x4*)(bvp + lr * 8);
            f32x4 bb1 = *(const f32x4*)(bvp + lr * 8 + 4);
            float bbv[8] = {bb0[0], bb0[1], bb0[2], bb0[3],
                            bb1[0], bb1[1], bb1[2], bb1[3]};
#pragma unroll
            for (int j = 0; j < 4; ++j) {
                int row = rb + lk * 4 + j;
                if (row >= N_VERT) continue;
                uint32 d[4];
#pragma unroll
                for (int p = 0; p < 4; ++p)
                    d[p] = f2bf_bits(acc[2 * p][j] + bbv[2 * p]) |
                           (f2bf_bits(acc[2 * p + 1][j] + bbv[2 * p + 1]) << 16);
                *(uint4*)((uint8*)zcp + (size_t)row * 256 + lr * 16) =
                    make_uint4(d[0], d[1], d[2], d[3]);
            }
        } else {
            uint8* pay = (w == 1) ? pay_i : pay_n;
#pragma unroll
            for (int j = 0; j < 4; ++j) {
                int row = rb + lk * 4 + j;
                if (row >= N_VERT) continue;
                uint32 lo, hi;
                lo = __builtin_amdgcn_cvt_pk_fp8_f32(acc[0][j], acc[1][j], 0, false);
                lo = __builtin_amdgcn_cvt_pk_fp8_f32(acc[2][j], acc[3][j], lo, true);
                hi = __builtin_amdgcn_cvt_pk_fp8_f32(acc[4][j], acc[5][j], 0, false);
                hi = __builtin_amdgcn_cvt_pk_fp8_f32(acc[6][j], acc[7][j], hi, true);
                *(uint2*)(pay + (size_t)row * 128 + lr * 8) = make_uint2(lo, hi);
            }
        }
    }
}

// ---------------------------------------------------------------------------
// Kernel B: gather-aggregate on permuted fp8 payload. EXACT R11/R15 config
// (3125 blocks, no pass branch) — proven ~40 us fabric floor.
// ---------------------------------------------------------------------------
__global__ __launch_bounds__(256) void agg_kernel(
    const uint8*  __restrict__ pay_i,
    const uint8*  __restrict__ pay_n,
    const unsigned short* __restrict__ zcp,
    const int4*   __restrict__ int_idx4,
    const int4*   __restrict__ nh_idx4,
    const float4* __restrict__ int_e4,
    const float4* __restrict__ nh_e4,
    float* __restrict__ z)
{
    const int lane = threadIdx.x & 63;
    const int wave = threadIdx.x >> 6;
    const int vg   = lane >> 4;
    const int fg   = lane & 15;
    const int i    = blockIdx.x * 16 + wave * 4 + vg;

    float a_i[8], a_n[8];
#pragma unroll
    for (int j = 0; j < 8; ++j) { a_i[j] = 0.f; a_n[j] = 0.f; }
    int ci = 0, cn = 0;

    // ---------------- interface edges ----------------
    {
        int sidx[KNBR]; float f[KNBR];
#pragma unroll
        for (int q = 0; q < 5; ++q) {
            int4   a = int_idx4[i * 5 + q];
            float4 e = int_e4[i * 5 + q];
            int   av[4] = {a.x, a.y, a.z, a.w};
            float ev[4] = {e.x, e.y, e.z, e.w};
#pragma unroll
            for (int j = 0; j < 4; ++j) {
                bool v = av[j] >= 0;
                ci += v;
                sidx[4 * q + j] = v ? av[j] : 0;
                f[4 * q + j]    = v ? ev[j] : 0.f;
            }
        }
        uint2 g[KNBR];
#pragma unroll
        for (int k = 0; k < KNBR; ++k)
            g[k] = *(const uint2*)(pay_i + (size_t)sidx[k] * 128 + fg * 8);
#pragma unroll
        for (int k = 0; k < KNBR; ++k) {
            float e = f[k];
            f32x2 p01 = __builtin_amdgcn_cvt_pk_f32_fp8((int)g[k].x, false);
            f32x2 p23 = __builtin_amdgcn_cvt_pk_f32_fp8((int)g[k].x, true);
            f32x2 p45 = __builtin_amdgcn_cvt_pk_f32_fp8((int)g[k].y, false);
            f32x2 p67 = __builtin_amdgcn_cvt_pk_f32_fp8((int)g[k].y, true);
            a_i[0] = fmaf(p01[0], e, a_i[0]);
            a_i[1] = fmaf(p01[1], e, a_i[1]);
            a_i[2] = fmaf(p23[0], e, a_i[2]);
            a_i[3] = fmaf(p23[1], e, a_i[3]);
            a_i[4] = fmaf(p45[0], e, a_i[4]);
            a_i[5] = fmaf(p45[1], e, a_i[5]);
            a_i[6] = fmaf(p67[0], e, a_i[6]);
            a_i[7] = fmaf(p67[1], e, a_i[7]);
        }
    }
    // ---------------- neighborhood edges ----------------
    {
        int sidx[KNBR]; float f[KNBR];
#pragma unroll
        for (int q = 0; q < 5; ++q) {
            int4   a = nh_idx4[i * 5 + q];
            float4 e = nh_e4[i * 5 + q];
            int   av[4] = {a.x, a.y, a.z, a.w};
            float ev[4] = {e.x, e.y, e.z, e.w};
#pragma unroll
            for (int j = 0; j < 4; ++j) {
                bool v = av[j] >= 0;
                cn += v;
                sidx[4 * q + j] = v ? av[j] : 0;
                f[4 * q + j]    = v ? ev[j] : 0.f;
            }
        }
        uint2 g[KNBR];
#pragma unroll
        for (int k = 0; k < KNBR; ++k)
            g[k] = *(const uint2*)(pay_n + (size_t)sidx[k] * 128 + fg * 8);
#pragma unroll
        for (int k = 0; k < KNBR; ++k) {
            float e = f[k];
            f32x2 p01 = __builtin_amdgcn_cvt_pk_f32_fp8((int)g[k].x, false);
            f32x2 p23 = __builtin_amdgcn_cvt_pk_f32_fp8((int)g[k].x, true);
            f32x2 p45 = __builtin_amdgcn_cvt_pk_f32_fp8((int)g[k].y, false);
            f32x2 p67 = __builtin_amdgcn_cvt_pk_f32_fp8((int)g[k].y, true);
            a_n[0] = fmaf(p01[0], e, a_n[0]);
            a_n[1] = fmaf(p01[1], e, a_n[1]);
            a_n[2] = fmaf(p23[0], e, a_n[2]);
            a_n[3] = fmaf(p23[1], e, a_n[3]);
            a_n[4] = fmaf(p45[0], e, a_n[4]);
            a_n[5] = fmaf(p45[1], e, a_n[5]);
            a_n[6] = fmaf(p67[0], e, a_n[6]);
            a_n[7] = fmaf(p67[1], e, a_n[7]);
        }
    }

    float ri = 1.f / (float)max(ci, 1);
    float rn = 1.f / (float)max(cn, 1);

    // zcp row (bias pre-added); un-permute via 8 dword stores
    uint4 zq = *(const uint4*)(zcp + (size_t)i * 128 + fg * 8);
    uint32 zd[4] = {zq.x, zq.y, zq.z, zq.w};
    float* zrow = z + (size_t)i * F + fg;
#pragma unroll
    for (int t = 0; t < 8; ++t) {
        uint32 dw = zd[t >> 1];
        float zc = __uint_as_float((t & 1) ? (dw & 0xffff0000u) : (dw << 16));
        float r  = zc + a_i[t] * ri + a_n[t] * rn;
        zrow[t * 16] = fmaxf(r, 0.f);      // filter t*16+fg
    }
}

extern "C" void kernel_launch(void* const* d_in, const int* in_sizes, int n_in,
                              void* d_out, int out_size, void* d_ws, size_t ws_size,
                              hipStream_t stream) {
    const float* vert    = (const float*)d_in[0];
    const int*   nh_idx  = (const int*)  d_in[1];
    const int*   int_idx = (const int*)  d_in[2];
    const float* nh_e    = (const float*)d_in[3];
    const float* int_e   = (const float*)d_in[4];
    const int*   is_int  = (const int*)  d_in[5];
    const float* Wc      = (const float*)d_in[6];
    const float* Wi      = (const float*)d_in[7];
    const float* Wn      = (const float*)d_in[8];
    const float* bv      = (const float*)d_in[9];

    float* z        = (float*)d_out;                     // [N, F]
    float* out_rest = z + (size_t)N_VERT * F;            // passthrough chunks

    uint8* pay_i = (uint8*)d_ws;                         // fp8 [N][128] permuted
    uint8* pay_n = pay_i + (size_t)N_VERT * F;           // fp8 [N][128] permuted
    ushort16* zcp = (ushort16*)(pay_n + (size_t)N_VERT * F); // bf16 [N][128] permuted (+bias)
    float* bvp   = (float*)(zcp + (size_t)N_VERT * F);   // f32 [128] permuted
    ushort16* Wt = (ushort16*)(bvp + F);                 // bf16 fragment-linear

    wconv_kernel<<<(3 * F * F + 255) / 256, 256, 0, stream>>>(Wc, Wi, Wn, bv, Wt, bvp);
    mfma_proj_kernel<<<NBLK + PASS_BLOCKS, 256, 0, stream>>>(
        vert, Wt, bvp, zcp, pay_i, pay_n,
        nh_idx, int_idx, nh_e, int_e, is_int, out_rest);
    agg_kernel<<<AGG_BLOCKS, 256, 0, stream>>>(
        pay_i, pay_n, (const unsigned short*)zcp,
        (const int4*)int_idx, (const int4*)nh_idx,
        (const float4*)int_e, (const float4*)nh_e, z);
}

// Round 17
// 66.398 us; speedup vs baseline: 1.3612x; 1.0481x over previous
//
#include <hip/hip_runtime.h>

#define N_VERT 50000
#define KNBR 20
#define F 128
#define NBLK 782        // ceil(50000/64)
#define AGG_BLOCKS 3125 // N_VERT/16
#define PASS_BLOCKS 1024

typedef unsigned int uint32;
typedef unsigned short ushort16;
typedef unsigned char uint8;
typedef __attribute__((ext_vector_type(8))) short bf16x8;
typedef __attribute__((ext_vector_type(4))) float f32x4;
typedef __attribute__((ext_vector_type(2))) float f32x2;

// global->LDS direct DMA, 16B per lane; LDS dest is wave-uniform base + lane*16
#define GLOAD_LDS16(g, l) __builtin_amdgcn_global_load_lds(                 \
    (__attribute__((address_space(1))) void*)(g),                           \
    (__attribute__((address_space(3))) void*)(l), 16, 0, 0)

__device__ __forceinline__ uint32 f2bf_bits(float x) {
    uint32 u = __float_as_uint(x);
    u += 0x7fff + ((u >> 16) & 1);        // round-to-nearest-even
    return u >> 16;
}

// ---------------------------------------------------------------------------
// Kernel W: weights -> bf16 fragment-linear Wt + permuted bias bvp.
// Permuted column order: c' = lr*8 + nt  <->  filter nt*16 + lr.
// ---------------------------------------------------------------------------
__global__ __launch_bounds__(256) void wconv_kernel(
    const float* __restrict__ Wc, const float* __restrict__ Wi,
    const float* __restrict__ Wn, const float* __restrict__ bv,
    ushort16* __restrict__ Wt, float* __restrict__ bvp)
{
    int t = blockIdx.x * 256 + threadIdx.x;
    if (blockIdx.x == 0 && threadIdx.x < 128) {
        int c = threadIdx.x;                    // c' = lr*8+nt
        bvp[c] = bv[(c & 7) * 16 + (c >> 3)];   // filter nt*16+lr
    }
    if (t >= 3 * F * F) return;
    int w    = t >> 14;
    int r    = t & 16383;
    int kk   = r >> 12;
    int r2   = r & 4095;
    int nt   = r2 >> 9;
    int r3   = r2 & 511;
    int lane = r3 >> 3;
    int e    = r3 & 7;
    int k = kk * 32 + (lane >> 4) * 8 + e;
    int n = nt * 16 + (lane & 15);
    const float* W = (w == 0) ? Wc : ((w == 1) ? Wi : Wn);
    Wt[t] = (ushort16)f2bf_bits(W[k * F + n]);
}

// ---------------------------------------------------------------------------
// Kernel A: FUSED projections + FOLDED passthrough.
// vs R16: B-staging via global_load_lds (ZERO staging VGPRs -> allocator
// can't flatten it, no across-barrier register liveness -> no R13 spill).
// Phase loop: stage(w) -> barrier (vmcnt drain) -> MFMA from LDS -> epilogue
// -> barrier -> stage(w+1). LDS 32 KB -> 5 blocks/CU; one block's stage
// stall hides under the other blocks' compute.
// ---------------------------------------------------------------------------
__global__ __launch_bounds__(256) void mfma_proj_kernel(
    const float*    __restrict__ vert,
    const ushort16* __restrict__ Wt,
    const float*    __restrict__ bvp,
    ushort16* __restrict__ zcp,
    uint8* __restrict__ pay_i,
    uint8* __restrict__ pay_n,
    const int*   __restrict__ nh_idx,  const int*   __restrict__ int_idx,
    const float* __restrict__ nh_e,    const float* __restrict__ int_e,
    const int*   __restrict__ is_int,  float* __restrict__ out_rest)
{
    __shared__ uint4 wlds[32 * 64];   // 32 KB: one w's 32 B-fragments

    if (blockIdx.x >= NBLK) {
        // ---------------- passthrough section ----------------
        const size_t NK    = (size_t)N_VERT * KNBR;
        const size_t total = 4 * NK + N_VERT;
        size_t t0 = (size_t)(blockIdx.x - NBLK) * 256 + threadIdx.x;
        for (size_t t = t0; t < total; t += (size_t)PASS_BLOCKS * 256) {
            float v;
            if      (t <     NK) v = (float)nh_idx[t];
            else if (t < 2 * NK) v = (float)int_idx[t - NK];
            else if (t < 3 * NK) v = nh_e[t - 2 * NK];
            else if (t < 4 * NK) v = int_e[t - 3 * NK];
            else                 v = (float)is_int[t - 4 * NK];
            out_rest[t] = v;
        }
        return;
    }

    const int wave = threadIdx.x >> 6;
    const int lane = threadIdx.x & 63;
    const int lr   = lane & 15;
    const int lk   = lane >> 4;
    const int rb   = (blockIdx.x * 4 + wave) * 16;

    const uint4* gW = (const uint4*)Wt;

    // ---- issue phase-0 staging first (latency hides under afrag build) ----
#pragma unroll
    for (int nt = 0; nt < 8; ++nt)
        GLOAD_LDS16(gW + (size_t)(wave * 8 + nt) * 64 + lane,
                    &wlds[(wave * 8 + nt) * 64]);

    // ---- A fragments: V rows read ONCE, converted inline (clamped tail) ----
    int rowA = rb + lr; if (rowA > N_VERT - 1) rowA = N_VERT - 1;
    const float* vrow = vert + (size_t)rowA * F;
    bf16x8 afrag[4];
#pragma unroll
    for (int kk = 0; kk < 4; ++kk) {
        const float* p = vrow + kk * 32 + lk * 8;
        f32x4 lo = *(const f32x4*)p;
        f32x4 hi = *(const f32x4*)(p + 4);
#pragma unroll
        for (int j = 0; j < 4; ++j) {
            afrag[kk][j]     = (short)f2bf_bits(lo[j]);
            afrag[kk][4 + j] = (short)f2bf_bits(hi[j]);
        }
    }

#pragma unroll
    for (int w = 0; w < 3; ++w) {
        __syncthreads();   // stage w complete (compiler drains vmcnt before barrier)

        f32x4 acc[8];
#pragma unroll
        for (int nt = 0; nt < 8; ++nt) acc[nt] = (f32x4)(0.f);

#pragma unroll
        for (int kk = 0; kk < 4; ++kk)
#pragma unroll
            for (int nt = 0; nt < 8; ++nt) {
                bf16x8 b = *(const bf16x8*)&wlds[(kk * 8 + nt) * 64 + lane];
                acc[nt] = __builtin_amdgcn_mfma_f32_16x16x32_bf16(
                    afrag[kk], b, acc[nt], 0, 0, 0);
            }

        if (w < 2) {
            __syncthreads();   // WAR: all waves done reading phase w
#pragma unroll
            for (int nt = 0; nt < 8; ++nt)
                GLOAD_LDS16(gW + (size_t)(((w + 1) * 4 + wave) * 8 + nt) * 64 + lane,
                            &wlds[(wave * 8 + nt) * 64]);
        }

        if (w == 0) {
            // bias pre-add (filter nt*16+lr -> bvp[lr*8+nt]), bf16 permuted store
            f32x4 bb0 = *(const f32x4*)(bvp + lr * 8);
            f32x4 bb1 = *(const f32x4*)(bvp + lr * 8 + 4);
            float bbv[8] = {bb0[0], bb0[1], bb0[2], bb0[3],
                            bb1[0], bb1[1], bb1[2], bb1[3]};
#pragma unroll
            for (int j = 0; j < 4; ++j) {
                int row = rb + lk * 4 + j;
                if (row >= N_VERT) continue;
                uint32 d[4];
#pragma unroll
                for (int p = 0; p < 4; ++p)
                    d[p] = f2bf_bits(acc[2 * p][j] + bbv[2 * p]) |
                           (f2bf_bits(acc[2 * p + 1][j] + bbv[2 * p + 1]) << 16);
                *(uint4*)((uint8*)zcp + (size_t)row * 256 + lr * 16) =
                    make_uint4(d[0], d[1], d[2], d[3]);
            }
        } else {
            uint8* pay = (w == 1) ? pay_i : pay_n;
#pragma unroll
            for (int j = 0; j < 4; ++j) {
                int row = rb + lk * 4 + j;
                if (row >= N_VERT) continue;
                uint32 lo, hi;
                lo = __builtin_amdgcn_cvt_pk_fp8_f32(acc[0][j], acc[1][j], 0, false);
                lo = __builtin_amdgcn_cvt_pk_fp8_f32(acc[2][j], acc[3][j], lo, true);
                hi = __builtin_amdgcn_cvt_pk_fp8_f32(acc[4][j], acc[5][j], 0, false);
                hi = __builtin_amdgcn_cvt_pk_fp8_f32(acc[6][j], acc[7][j], hi, true);
                *(uint2*)(pay + (size_t)row * 128 + lr * 8) = make_uint2(lo, hi);
            }
        }
    }
}

// ---------------------------------------------------------------------------
// Kernel B: gather-aggregate on permuted fp8 payload. EXACT R11/R15 config
// (3125 blocks, no pass branch) — proven ~40 us fabric floor.
// ---------------------------------------------------------------------------
__global__ __launch_bounds__(256) void agg_kernel(
    const uint8*  __restrict__ pay_i,
    const uint8*  __restrict__ pay_n,
    const unsigned short* __restrict__ zcp,
    const int4*   __restrict__ int_idx4,
    const int4*   __restrict__ nh_idx4,
    const float4* __restrict__ int_e4,
    const float4* __restrict__ nh_e4,
    float* __restrict__ z)
{
    const int lane = threadIdx.x & 63;
    const int wave = threadIdx.x >> 6;
    const int vg   = lane >> 4;
    const int fg   = lane & 15;
    const int i    = blockIdx.x * 16 + wave * 4 + vg;

    float a_i[8], a_n[8];
#pragma unroll
    for (int j = 0; j < 8; ++j) { a_i[j] = 0.f; a_n[j] = 0.f; }
    int ci = 0, cn = 0;

    // ---------------- interface edges ----------------
    {
        int sidx[KNBR]; float f[KNBR];
#pragma unroll
        for (int q = 0; q < 5; ++q) {
            int4   a = int_idx4[i * 5 + q];
            float4 e = int_e4[i * 5 + q];
            int   av[4] = {a.x, a.y, a.z, a.w};
            float ev[4] = {e.x, e.y, e.z, e.w};
#pragma unroll
            for (int j = 0; j < 4; ++j) {
                bool v = av[j] >= 0;
                ci += v;
                sidx[4 * q + j] = v ? av[j] : 0;
                f[4 * q + j]    = v ? ev[j] : 0.f;
            }
        }
        uint2 g[KNBR];
#pragma unroll
        for (int k = 0; k < KNBR; ++k)
            g[k] = *(const uint2*)(pay_i + (size_t)sidx[k] * 128 + fg * 8);
#pragma unroll
        for (int k = 0; k < KNBR; ++k) {
            float e = f[k];
            f32x2 p01 = __builtin_amdgcn_cvt_pk_f32_fp8((int)g[k].x, false);
            f32x2 p23 = __builtin_amdgcn_cvt_pk_f32_fp8((int)g[k].x, true);
            f32x2 p45 = __builtin_amdgcn_cvt_pk_f32_fp8((int)g[k].y, false);
            f32x2 p67 = __builtin_amdgcn_cvt_pk_f32_fp8((int)g[k].y, true);
            a_i[0] = fmaf(p01[0], e, a_i[0]);
            a_i[1] = fmaf(p01[1], e, a_i[1]);
            a_i[2] = fmaf(p23[0], e, a_i[2]);
            a_i[3] = fmaf(p23[1], e, a_i[3]);
            a_i[4] = fmaf(p45[0], e, a_i[4]);
            a_i[5] = fmaf(p45[1], e, a_i[5]);
            a_i[6] = fmaf(p67[0], e, a_i[6]);
            a_i[7] = fmaf(p67[1], e, a_i[7]);
        }
    }
    // ---------------- neighborhood edges ----------------
    {
        int sidx[KNBR]; float f[KNBR];
#pragma unroll
        for (int q = 0; q < 5; ++q) {
            int4   a = nh_idx4[i * 5 + q];
            float4 e = nh_e4[i * 5 + q];
            int   av[4] = {a.x, a.y, a.z, a.w};
            float ev[4] = {e.x, e.y, e.z, e.w};
#pragma unroll
            for (int j = 0; j < 4; ++j) {
                bool v = av[j] >= 0;
                cn += v;
                sidx[4 * q + j] = v ? av[j] : 0;
                f[4 * q + j]    = v ? ev[j] : 0.f;
            }
        }
        uint2 g[KNBR];
#pragma unroll
        for (int k = 0; k < KNBR; ++k)
            g[k] = *(const uint2*)(pay_n + (size_t)sidx[k] * 128 + fg * 8);
#pragma unroll
        for (int k = 0; k < KNBR; ++k) {
            float e = f[k];
            f32x2 p01 = __builtin_amdgcn_cvt_pk_f32_fp8((int)g[k].x, false);
            f32x2 p23 = __builtin_amdgcn_cvt_pk_f32_fp8((int)g[k].x, true);
            f32x2 p45 = __builtin_amdgcn_cvt_pk_f32_fp8((int)g[k].y, false);
            f32x2 p67 = __builtin_amdgcn_cvt_pk_f32_fp8((int)g[k].y, true);
            a_n[0] = fmaf(p01[0], e, a_n[0]);
            a_n[1] = fmaf(p01[1], e, a_n[1]);
            a_n[2] = fmaf(p23[0], e, a_n[2]);
            a_n[3] = fmaf(p23[1], e, a_n[3]);
            a_n[4] = fmaf(p45[0], e, a_n[4]);
            a_n[5] = fmaf(p45[1], e, a_n[5]);
            a_n[6] = fmaf(p67[0], e, a_n[6]);
            a_n[7] = fmaf(p67[1], e, a_n[7]);
        }
    }

    float ri = 1.f / (float)max(ci, 1);
    float rn = 1.f / (float)max(cn, 1);

    // zcp row (bias pre-added); un-permute via 8 dword stores
    uint4 zq = *(const uint4*)(zcp + (size_t)i * 128 + fg * 8);
    uint32 zd[4] = {zq.x, zq.y, zq.z, zq.w};
    float* zrow = z + (size_t)i * F + fg;
#pragma unroll
    for (int t = 0; t < 8; ++t) {
        uint32 dw = zd[t >> 1];
        float zc = __uint_as_float((t & 1) ? (dw & 0xffff0000u) : (dw << 16));
        float r  = zc + a_i[t] * ri + a_n[t] * rn;
        zrow[t * 16] = fmaxf(r, 0.f);      // filter t*16+fg
    }
}

extern "C" void kernel_launch(void* const* d_in, const int* in_sizes, int n_in,
                              void* d_out, int out_size, void* d_ws, size_t ws_size,
                              hipStream_t stream) {
    const float* vert    = (const float*)d_in[0];
    const int*   nh_idx  = (const int*)  d_in[1];
    const int*   int_idx = (const int*)  d_in[2];
    const float* nh_e    = (const float*)d_in[3];
    const float* int_e   = (const float*)d_in[4];
    const int*   is_int  = (const int*)  d_in[5];
    const float* Wc      = (const float*)d_in[6];
    const float* Wi      = (const float*)d_in[7];
    const float* Wn      = (const float*)d_in[8];
    const float* bv      = (const float*)d_in[9];

    float* z        = (float*)d_out;                     // [N, F]
    float* out_rest = z + (size_t)N_VERT * F;            // passthrough chunks

    uint8* pay_i = (uint8*)d_ws;                         // fp8 [N][128] permuted
    uint8* pay_n = pay_i + (size_t)N_VERT * F;           // fp8 [N][128] permuted
    ushort16* zcp = (ushort16*)(pay_n + (size_t)N_VERT * F); // bf16 [N][128] permuted (+bias)
    float* bvp   = (float*)(zcp + (size_t)N_VERT * F);   // f32 [128] permuted
    ushort16* Wt = (ushort16*)(bvp + F);                 // bf16 fragment-linear

    wconv_kernel<<<(3 * F * F + 255) / 256, 256, 0, stream>>>(Wc, Wi, Wn, bv, Wt, bvp);
    mfma_proj_kernel<<<NBLK + PASS_BLOCKS, 256, 0, stream>>>(
        vert, Wt, bvp, zcp, pay_i, pay_n,
        nh_idx, int_idx, nh_e, int_e, is_int, out_rest);
    agg_kernel<<<AGG_BLOCKS, 256, 0, stream>>>(
        pay_i, pay_n, (const unsigned short*)zcp,
        (const int4*)int_idx, (const int4*)nh_idx,
        (const float4*)int_e, (const float4*)nh_e, z);
}